// Round 9
// baseline (714.428 us; speedup 1.0000x reference)
//
#include <hip/hip_runtime.h>
#include <cmath>

#define B_ 4
#define T_ 4096
#define D_ 1024

typedef __attribute__((ext_vector_type(4))) float f32x4;
typedef __attribute__((ext_vector_type(2))) float f32x2;
typedef __attribute__((ext_vector_type(8))) short s16x8;
typedef _Float16 h16x8 __attribute__((ext_vector_type(8)));
typedef _Float16 h16x4 __attribute__((ext_vector_type(4)));

__device__ __forceinline__ f32x4 mfma_bf16(s16x8 a, s16x8 b, f32x4 c) {
    return __builtin_amdgcn_mfma_f32_16x16x32_bf16(a, b, c, 0, 0, 0);
}
__device__ __forceinline__ f32x4 mfma_f16(h16x8 a, h16x8 b, f32x4 c) {
    return __builtin_amdgcn_mfma_f32_16x16x32_f16(a, b, c, 0, 0, 0);
}
__device__ __forceinline__ unsigned short f2bf(float f) {
    union { float f; unsigned int u; } v; v.f = f;
    unsigned int r = v.u + 0x7FFFu + ((v.u >> 16) & 1u);
    return (unsigned short)(r >> 16);
}
__device__ __forceinline__ unsigned short f2h(float f) {
    union { _Float16 h; unsigned short u; } v; v.h = (_Float16)f;
    return v.u;
}
// DPP lane permute within 16-lane rows (VALU-speed reduction)
template <int CTRL>
__device__ __forceinline__ float dppf(float x) {
    return __int_as_float(
        __builtin_amdgcn_mov_dpp(__float_as_int(x), CTRL, 0xF, 0xF, true));
}
__device__ __forceinline__ float rowmax16(float v) {
    v = fmaxf(v, dppf<0xB1>(v));
    v = fmaxf(v, dppf<0x4E>(v));
    v = fmaxf(v, dppf<0x141>(v));
    v = fmaxf(v, dppf<0x140>(v));
    return v;
}
__device__ __forceinline__ float rowsum16(float v) {
    v += dppf<0xB1>(v);
    v += dppf<0x4E>(v);
    v += dppf<0x141>(v);
    v += dppf<0x140>(v);
    return v;
}

// ---------------- kernel 1: repack fp32 weights to bf16 w_t[p][h][d][i] ----
__global__ __launch_bounds__(256) void k_wtrans(const float* __restrict__ wq,
                                                const float* __restrict__ wk,
                                                const float* __restrict__ wv,
                                                unsigned short* __restrict__ wt) {
    int p = blockIdx.x >> 4;   // 0..2
    int h = blockIdx.x & 15;
    const float* src = (p == 0) ? wq : (p == 1) ? wk : wv;
    unsigned short* dst = wt + (size_t)((p * 16 + h) * 64) * 64;
    for (int idx = threadIdx.x; idx < 64 * 64; idx += 256) {
        int d = idx >> 6, i = idx & 63;
        dst[d * 64 + i] = f2bf(src[i * 1024 + d * 16 + h]);   // w[i][d][h]
    }
}

// ---------------- kernel 2: QKV projection + fused RoPE ---------------------
// R4-proven structure. Changes: (a) gamma=1/32 folded into Q (exact pow2, so
// k_attn logits need no scaling); (b) V stored f16 (PV now runs f16 MFMA and
// P/S staging is f16 — |V| ~ O(1), f16 has better mantissa than bf16).
__global__ __launch_bounds__(256, 3) void k_qkv(const float* __restrict__ x,
                                             const unsigned short* __restrict__ wt,
                                             unsigned short* __restrict__ Qt,
                                             unsigned short* __restrict__ Kt,
                                             unsigned short* __restrict__ Vt) {
    int bid = blockIdx.x;
    int hp  = bid >> 8;          // head pair 0..7
    int b   = (bid >> 6) & 3;
    int tc  = bid & 63;          // token chunk (64 tokens)
    int t0  = tc * 64;
    int tid = threadIdx.x, w = tid >> 6, lane = tid & 63;
    int quad = lane >> 4, l16 = lane & 15;

    __shared__ alignas(16) unsigned short xh[2 * 64 * 72];   // [hh][t][i], pad 72
    __shared__ alignas(16) unsigned short outl[64 * 68];     // staging tile, pad 68

    for (int n = tid; n < 4096; n += 256) {
        int t = n >> 6, i = n & 63;
        f32x2 v = *(const f32x2*)&x[(size_t)(b * T_ + t0 + t) * D_ + i * 16 + 2 * hp];
        xh[t * 72 + i]        = f2bf(v.x);
        xh[4608 + t * 72 + i] = f2bf(v.y);
    }
    __syncthreads();

    s16x8 xf[2][2];
    #pragma unroll
    for (int hh = 0; hh < 2; ++hh)
        #pragma unroll
        for (int kc = 0; kc < 2; ++kc)
            xf[hh][kc] = *(const s16x8*)&xh[hh * 4608 + (16 * w + l16) * 72 + kc * 32 + quad * 8];

    f32x4 acc[3][2][4];
    #pragma unroll
    for (int p = 0; p < 3; ++p)
        #pragma unroll
        for (int hh = 0; hh < 2; ++hh)
            #pragma unroll
            for (int nt = 0; nt < 4; ++nt)
                acc[p][hh][nt] = (f32x4){0.f, 0.f, 0.f, 0.f};

    #pragma unroll
    for (int p = 0; p < 3; ++p)
        #pragma unroll
        for (int hh = 0; hh < 2; ++hh)
            #pragma unroll
            for (int nt = 0; nt < 4; ++nt)
                #pragma unroll
                for (int kc = 0; kc < 2; ++kc) {
                    const s16x8 wf = *(const s16x8*)&wt[
                        (size_t)((p * 16 + 2 * hp + hh) * 64 + nt * 16 + l16) * 64 + kc * 32 + quad * 8];
                    if (p < 2)
                        acc[p][hh][nt] = mfma_bf16(xf[hh][kc], wf, acc[p][hh][nt]);
                    else
                        acc[p][hh][nt] = mfma_bf16(wf, xf[hh][kc], acc[p][hh][nt]);
                }

    const float GAM = 0.03125f;   // 1/sqrt(1024), folded into Q
    #pragma unroll
    for (int nt = 0; nt < 4; ++nt) {
        int d = nt * 16 + l16;
        float f = exp2f((float)(d * 8 + hp) * -0.02595256324130751f); // -log2(1e4)/512
        #pragma unroll
        for (int r = 0; r < 4; ++r) {
            float ang = (float)(t0 + 16 * w + quad * 4 + r) * f;
            float s, c;
            __sincosf(ang, &s, &c);
            float a0 = acc[0][0][nt][r], a1 = acc[0][1][nt][r];
            acc[0][0][nt][r] = (a0 * c - a1 * s) * GAM;
            acc[0][1][nt][r] = (a0 * s + a1 * c) * GAM;
            float k0 = acc[1][0][nt][r], k1 = acc[1][1][nt][r];
            acc[1][0][nt][r] = k0 * c - k1 * s;
            acc[1][1][nt][r] = k0 * s + k1 * c;
        }
    }

    #pragma unroll
    for (int p = 0; p < 3; ++p)
        #pragma unroll
        for (int hh = 0; hh < 2; ++hh) {
            __syncthreads();
            if (p < 2) {
                #pragma unroll
                for (int nt = 0; nt < 4; ++nt)
                    #pragma unroll
                    for (int r = 0; r < 4; ++r)
                        outl[(16 * w + quad * 4 + r) * 68 + nt * 16 + l16] = f2bf(acc[p][hh][nt][r]);
            } else {
                #pragma unroll
                for (int mt = 0; mt < 4; ++mt)
                    #pragma unroll
                    for (int r = 0; r < 4; ++r)
                        outl[(mt * 16 + quad * 4 + r) * 68 + 16 * w + l16] = f2h(acc[p][hh][mt][r]);
            }
            __syncthreads();
            int h = 2 * hp + hh;
            if (p < 2) {
                unsigned short* g = (p == 0 ? Qt : Kt) + ((size_t)(b * 16 + h) * T_ + t0) * 64;
                for (int n = 2 * tid; n < 4096; n += 512) {
                    int t = n >> 6, dd = n & 63;
                    *(unsigned int*)(g + n) = *(const unsigned int*)&outl[t * 68 + dd];
                }
            } else {
                // tile-blocked V (f16): [h][tile(128)][d64][t&31], tile = t>>5
                unsigned short* g = Vt + (size_t)(b * 16 + h) * 64 * T_;
                for (int n = 2 * tid; n < 4096; n += 512) {
                    int d = n >> 6, tt = n & 63;
                    int tile = 2 * tc + (tt >> 5);
                    *(unsigned int*)(g + (size_t)tile * 2048 + d * 32 + (tt & 31)) =
                        *(const unsigned int*)&outl[d * 68 + tt];
                }
            }
        }
}

// ---------------- kernel 3: flash attention, KVBLK=128, f16 staging --------
// The 2 barriers/tile are structural (S_red and P are cross-wave transposes
// of the full-d=1024 logit), so the lever is paying them per MORE keys.
// KVBLK 64->128 enabled by f16 staging: S_red f16 [8][32][136] = 68KB (f32
// would be 132KB), partial-logit f16 error ~3e-4 << 0.028 threshold. Reduce
// uses packed v_pk_add_f16 (28 ops/128 keys). P,V f16 -> PV via f16 MFMA.
// gamma pre-folded into Q. 78.6KB LDS -> still 2 blocks/CU.
__global__ __launch_bounds__(512, 2) void k_attn(const unsigned short* __restrict__ Qt,
                                              const unsigned short* __restrict__ Kt,
                                              const unsigned short* __restrict__ Vt,
                                              float* __restrict__ out) {
    int bid = blockIdx.x;
    int b = (bid >> 1) & 3;                      // batch <- XCD pair (R3 win)
    int q = ((bid >> 3) & 31) * 2 + (bid & 1);   // 0..63
    int qt = (bid < 256) ? (127 - q) : q;        // heavy blocks first
    int q0 = qt * 32;
    int tid = threadIdx.x, w = tid >> 6, lane = tid & 63;
    int quad = lane >> 4, l16 = lane & 15;

    __shared__ alignas(16) _Float16 S_red[8][32][136];   // partial logits, 128 keys
    __shared__ alignas(16) _Float16 P_lds[32][136];      // P[q][key] f16
    __shared__ float alpha_s[32], l_st[32];

    const _Float16* Vh = (const _Float16*)Vt;

    // Q fragments (loop-invariant): B-operand, [q][d] d-contig, pre-scaled
    s16x8 qf[2][4];
    #pragma unroll
    for (int qs = 0; qs < 2; ++qs)
        #pragma unroll
        for (int c = 0; c < 4; ++c) {
            int dg = w * 128 + c * 32 + quad * 8;
            int head = dg >> 6, d64 = dg & 63;
            qf[qs][c] = *(const s16x8*)&Qt[((size_t)(b * 16 + head) * T_ + q0 + qs * 16 + l16) * 64 + d64];
        }

    f32x4 Y[8][2];
    #pragma unroll
    for (int mt = 0; mt < 8; ++mt) { Y[mt][0] = (f32x4){0,0,0,0}; Y[mt][1] = (f32x4){0,0,0,0}; }

    int rq = tid >> 4;              // softmax row 0..31 (16 lanes per row)
    int k16 = tid & 15;
    int kk8 = k16 * 8;              // 8 keys per thread
    int nkt = (qt >> 2) + 1;        // 128-key tiles
    float m_reg = -INFINITY, l_reg = 0.f;

    // ---- prologue: S(tile 0) = keys 0..127 into S_red (f16) ----
    #pragma unroll
    for (int kps = 0; kps < 8; ++kps) {
        f32x4 S0 = (f32x4){0,0,0,0}, S1 = (f32x4){0,0,0,0};
        #pragma unroll
        for (int c = 0; c < 4; ++c) {
            int dg = w * 128 + c * 32 + quad * 8;
            int head = dg >> 6, d64 = dg & 63;
            s16x8 kf = *(const s16x8*)&Kt[((size_t)(b * 16 + head) * T_ + kps * 16 + l16) * 64 + d64];
            S0 = mfma_bf16(kf, qf[0][c], S0);
            S1 = mfma_bf16(kf, qf[1][c], S1);
        }
        h16x4 v0 = {(_Float16)S0[0], (_Float16)S0[1], (_Float16)S0[2], (_Float16)S0[3]};
        h16x4 v1 = {(_Float16)S1[0], (_Float16)S1[1], (_Float16)S1[2], (_Float16)S1[3]};
        *(h16x4*)&S_red[w][l16][kps * 16 + quad * 4]      = v0;
        *(h16x4*)&S_red[w][16 + l16][kps * 16 + quad * 4] = v1;
    }
    __syncthreads();

    h16x8 vfb[2][8];   // V fragments, double-buffered across 32-key subtiles

    for (int kt = 0; kt < nkt; ++kt) {
        int kbase = kt * 128;
        bool more = (kt + 1 < nkt);

        // ---- phase A: prefetch V sub0, then softmax(128 keys) ----
        #pragma unroll
        for (int mt = 0; mt < 8; ++mt) {
            int dg = w * 128 + mt * 16 + l16;
            int head = dg >> 6, d64 = dg & 63;
            vfb[0][mt] = *(const h16x8*)&Vh[
                (((size_t)(b * 16 + head) * 128 + 4 * kt) * 64 + d64) * 32 + quad * 8];
        }

        // packed f16 reduce over 8 wave-slices
        h16x8 acc = *(const h16x8*)&S_red[0][rq][kk8];
        #pragma unroll
        for (int sl = 1; sl < 8; ++sl)
            acc = acc + *(const h16x8*)&S_red[sl][rq][kk8];

        float s[8], p[8];
        int qg = q0 + rq;
        #pragma unroll
        for (int i = 0; i < 8; ++i) {
            float si = (float)acc[i];
            s[i] = (kbase + kk8 + i > qg) ? -INFINITY : si;
        }
        float mx = fmaxf(fmaxf(fmaxf(s[0], s[1]), fmaxf(s[2], s[3])),
                         fmaxf(fmaxf(s[4], s[5]), fmaxf(s[6], s[7])));
        mx = rowmax16(mx);
        // defer-max (THR=8): alpha==1 exactly unless max grew by >8
        float m_new = (mx > m_reg + 8.f) ? mx : m_reg;
        float alpha = __expf(m_reg - m_new);
        float ps = 0.f;
        #pragma unroll
        for (int i = 0; i < 8; ++i) { p[i] = __expf(s[i] - m_new); ps += p[i]; }
        ps = rowsum16(ps);
        l_reg = alpha * l_reg + ps;
        m_reg = m_new;
        if (k16 == 0) alpha_s[rq] = alpha;
        h16x8 pv = {(_Float16)p[0], (_Float16)p[1], (_Float16)p[2], (_Float16)p[3],
                    (_Float16)p[4], (_Float16)p[5], (_Float16)p[6], (_Float16)p[7]};
        *(h16x8*)&P_lds[rq][kk8] = pv;
        __syncthreads();

        // ---- phase B: PV (4 subtiles, V dbuf) + QK^T(next tile) interleaved
        float a0 = alpha_s[l16], a1 = alpha_s[16 + l16];
        int scale = __any((a0 < 1.f) || (a1 < 1.f));
        __builtin_amdgcn_s_setprio(1);
        if (scale) {
            #pragma unroll
            for (int mt = 0; mt < 8; ++mt) { Y[mt][0] *= a0; Y[mt][1] *= a1; }
        }
        #pragma unroll
        for (int ksub = 0; ksub < 4; ++ksub) {
            if (ksub < 3) {
                #pragma unroll
                for (int mt = 0; mt < 8; ++mt) {
                    int dg = w * 128 + mt * 16 + l16;
                    int head = dg >> 6, d64 = dg & 63;
                    vfb[(ksub + 1) & 1][mt] = *(const h16x8*)&Vh[
                        (((size_t)(b * 16 + head) * 128 + 4 * kt + ksub + 1) * 64 + d64) * 32 + quad * 8];
                }
            }
            h16x8 pf0 = *(const h16x8*)&P_lds[l16][ksub * 32 + quad * 8];
            h16x8 pf1 = *(const h16x8*)&P_lds[16 + l16][ksub * 32 + quad * 8];
            if (more) {
                #pragma unroll
                for (int kk = 0; kk < 2; ++kk) {
                    int kps = 2 * ksub + kk;
                    f32x4 S0 = (f32x4){0,0,0,0}, S1 = (f32x4){0,0,0,0};
                    #pragma unroll
                    for (int c = 0; c < 4; ++c) {
                        int dg = w * 128 + c * 32 + quad * 8;
                        int head = dg >> 6, d64 = dg & 63;
                        s16x8 kf = *(const s16x8*)&Kt[
                            ((size_t)(b * 16 + head) * T_ + kbase + 128 + kps * 16 + l16) * 64 + d64];
                        S0 = mfma_bf16(kf, qf[0][c], S0);
                        S1 = mfma_bf16(kf, qf[1][c], S1);
                    }
                    h16x4 v0 = {(_Float16)S0[0], (_Float16)S0[1], (_Float16)S0[2], (_Float16)S0[3]};
                    h16x4 v1 = {(_Float16)S1[0], (_Float16)S1[1], (_Float16)S1[2], (_Float16)S1[3]};
                    *(h16x4*)&S_red[w][l16][kps * 16 + quad * 4]      = v0;
                    *(h16x4*)&S_red[w][16 + l16][kps * 16 + quad * 4] = v1;
                }
            }
            #pragma unroll
            for (int mt = 0; mt < 8; ++mt) {
                Y[mt][0] = mfma_f16(vfb[ksub & 1][mt], pf0, Y[mt][0]);
                Y[mt][1] = mfma_f16(vfb[ksub & 1][mt], pf1, Y[mt][1]);
            }
        }
        __builtin_amdgcn_s_setprio(0);
        __syncthreads();
    }

    // ---- epilogue: publish l, normalize, map d->(h,d64)->e, store fp32 ----
    if (k16 == 0) l_st[rq] = l_reg;
    __syncthreads();
    float inv0 = 1.f / l_st[l16], inv1 = 1.f / l_st[16 + l16];
    #pragma unroll
    for (int mt = 0; mt < 8; ++mt)
        #pragma unroll
        for (int r = 0; r < 4; ++r) {
            int dg = w * 128 + mt * 16 + quad * 4 + r;
            int head = dg >> 6, d64 = dg & 63;
            int e = d64 * 16 + head;
            out[(size_t)(b * T_ + q0 + l16) * D_ + e]      = Y[mt][0][r] * inv0;
            out[(size_t)(b * T_ + q0 + 16 + l16) * D_ + e] = Y[mt][1][r] * inv1;
        }
}

extern "C" void kernel_launch(void* const* d_in, const int* in_sizes, int n_in,
                              void* d_out, int out_size, void* d_ws, size_t ws_size,
                              hipStream_t stream) {
    const float* x  = (const float*)d_in[0];
    const float* wq = (const float*)d_in[1];
    const float* wk = (const float*)d_in[2];
    const float* wv = (const float*)d_in[3];
    unsigned short* ws = (unsigned short*)d_ws;

    const size_t WT_ELEMS  = 3 * 16 * 64 * 64;          // 196608
    const size_t QKV_ELEMS = (size_t)B_ * 16 * T_ * 64; // 16777216 each
    const size_t NEED_BYTES = (WT_ELEMS + 3 * QKV_ELEMS) * sizeof(unsigned short);
    if (ws_size < NEED_BYTES) return;

    unsigned short* wt = ws;
    unsigned short* Qt = ws + WT_ELEMS;
    unsigned short* Kt = Qt + QKV_ELEMS;
    unsigned short* Vt = Kt + QKV_ELEMS;
    float* outp = (float*)d_out;

    k_wtrans<<<48, 256, 0, stream>>>(wq, wk, wv, wt);
    k_qkv<<<2048, 256, 0, stream>>>(x, wt, Qt, Kt, Vt);
    k_attn<<<512, 512, 0, stream>>>(Qt, Kt, Vt, outp);
}